// Round 4
// baseline (234.897 us; speedup 1.0000x reference)
//
#include <hip/hip_runtime.h>

#define TT 512
#define BB 512
#define NN 64
#define LN2F 0.69314718055994530942f
#define CGUARD 7     // normalization target: probed entries ~= 2^-CGUARD after scaling
#define NCHUNK 7     // 7 matrix chunks (waves 0..6); wave 7 does the gold score
#define CSTEP 73     // 7*73 = 511 steps covers t = 1..511

typedef _Float16 half8_t __attribute__((ext_vector_type(8)));
typedef float    f32x4   __attribute__((ext_vector_type(4)));

union AFrag { int u[4]; half8_t h; };

__device__ __forceinline__ float wave_sum(float v) {
    #pragma unroll
    for (int off = 32; off > 0; off >>= 1)
        v += __shfl_xor(v, off, 64);
    return v;
}

__device__ __forceinline__ int wave_sum_i(int v) {
    #pragma unroll
    for (int off = 32; off > 0; off >>= 1)
        v += __shfl_xor(v, off, 64);
    return v;
}

__device__ __forceinline__ float bcast_lane(float v, int lane) {
    return __uint_as_float(__builtin_amdgcn_readlane(__float_as_uint(v), lane));
}

// Zero the scalar output (harness poisons d_out with 0xAA before every launch).
__global__ void zero_kernel(float* __restrict__ out) {
    if (threadIdx.x == 0 && blockIdx.x == 0) out[0] = 0.0f;
}

// r16 = r15 (associative-scan / transfer-matrix chunking) de-risked:
//  - LDS 57.6 KB < 64 KB (7 chunk matrices instead of 8)
//  - wave 7 runs the gold score in parallel with the chunk scans
//  - d-probe widened to 4 column tiles (cols 0/16/32/48)
// Design: u_{t+1} = diag(w_t) E^T u_t is LINEAR, so the scan is a product of
// 64x64 transfer matrices. Block = 1 batch, waves 0..6 = time-chunks of 73
// steps. Each wave computes P~_c = prod diag(w_t)E^T as an f16 matmat scan
// using the r13/r14-verified A-fragment/sigma-permutation/B-feedback algebra
// (B now has distinct columns, 4 column tiles, P = I start; feedback stays
// lane-local per tile). w folds into A rows (4 exps + 32 v_pk_mul_f16/step);
// d probed from the previous pack, e_acc += d+2 exact. After one barrier,
// wave 0 applies u0 then P~_0..P~_6 as 7 matvec steps (A-frags from
// XOR-swizzled LDS rows) with per-step power-of-2 rescale.
__global__ __launch_bounds__(512) void crf_fwd_kernel(
    const float* __restrict__ emit,
    const float* __restrict__ trans,
    const float* __restrict__ strans,
    const float* __restrict__ etrans,
    const int*   __restrict__ target,
    const void*  __restrict__ maskp,
    float* __restrict__ out)
{
    const int b   = blockIdx.x;
    const int tid = threadIdx.x;
    const int k   = tid & 63;
    const int c   = tid >> 6;          // wave id: 0..6 = chunk, 7 = gold

    __shared__ __align__(16) unsigned short Pmat[NCHUNK][NN][NN];  // 56 KB, rows XOR-swizzled
    __shared__ float ibuf[NN];
    __shared__ int   esum[NCHUNK];

    const int*           mi32 = (const int*)maskp;
    const unsigned char* mi8  = (const unsigned char*)maskp;
    // mask[0,:] is all-true (lengths >= 1): byte encoding -> word0 == 0x01010101.
    const bool bytemode = (mi32[0] == 0x01010101);

    // len[b] = sum_t mask[t,b] (monotone mask), computed per wave (redundant, cheap)
    int cnt = 0;
    #pragma unroll
    for (int i = 0; i < TT / 64; ++i) {
        const size_t tb = (size_t)(i * 64 + k) * BB + b;
        cnt += bytemode ? (mi8[tb] != 0) : (mi32[tb] != 0);
    }
    const int len = wave_sum_i(cnt);   // wave-uniform

    const int q    = k >> 4;
    const int m15  = k & 15;
    const int base = 8 * (m15 >> 2) + 2 * (m15 & 3);   // sigma(g,m15) = 32*(g>>1)+(g&1)+base

    const f32x4 zero4 = {0.f, 0.f, 0.f, 0.f};

    if (c < NCHUNK) {
        // A fragments (r13/r14 structure, hardware-verified):
        // Af[g][kh] lane elem j = 0.25*exp(trans[(32kh+8q+j)][sigma(g,m15)]).
        half8_t Af[4][2];
        #pragma unroll
        for (int g = 0; g < 4; ++g) {
            const int nsg = 32 * (g >> 1) + (g & 1) + base;
            #pragma unroll
            for (int kh = 0; kh < 2; ++kh) {
                AFrag af;
                #pragma unroll
                for (int jp = 0; jp < 4; ++jp) {
                    const int krow = 32 * kh + 8 * q + 2 * jp;
                    const float e0 = 0.25f * __expf(trans[(krow + 0) * NN + nsg]);
                    const float e1 = 0.25f * __expf(trans[(krow + 1) * NN + nsg]);
                    af.u[jp] = __builtin_bit_cast(int, __builtin_amdgcn_cvt_pkrtz(e0, e1));
                }
                Af[g][kh] = af.h;
            }
        }

        // ---- chunk phase: P = I, then up to CSTEP matmat steps ----
        AFrag Bt0[4], Bt1[4];   // B-fragments per column tile n: col = 16n+m15
        #pragma unroll
        for (int n = 0; n < 4; ++n) {
            const int col = 16 * n + m15;
            #pragma unroll
            for (int r = 0; r < 4; ++r) {
                const int k0 = 8 * q + 2 * r;
                int v0 = 0;
                if (k0     == col) v0 |= 0x3c00;
                if (k0 + 1 == col) v0 |= 0x3c00 << 16;
                Bt0[n].u[r] = v0;
                int v1 = 0;
                if (32 + k0     == col) v1 |= 0x3c00;
                if (32 + k0 + 1 == col) v1 |= 0x3c00 << 16;
                Bt1[n].u[r] = v1;
            }
        }

        // d-probe: max f16 exponent over rows {0,1,32,33} x cols {0,16,32,48}
        // (lane 0's first pair of each tile).
        auto probe = [&]() -> int {
            int mm = 0;
            #pragma unroll
            for (int n = 0; n < 4; ++n) {
                const int p0 = __builtin_amdgcn_readfirstlane(Bt0[n].u[0]);
                const int p1 = __builtin_amdgcn_readfirstlane(Bt1[n].u[0]);
                int mA = p0 & 0x7fff, mB = (p0 >> 16) & 0x7fff;
                int mC = p1 & 0x7fff, mD = (p1 >> 16) & 0x7fff;
                mA = mA > mB ? mA : mB;
                mC = mC > mD ? mC : mD;
                mA = mA > mC ? mA : mC;
                mm = mm > mA ? mm : mA;
            }
            return (mm >> 10) - 15 + CGUARD;
        };

        int e_acc = 0;
        const int t0  = 1 + CSTEP * c;
        const int t1v = min(1 + CSTEP * (c + 1), len);   // steps t in [t0, t1v)
        const float* ebase = emit + (size_t)b * NN;

        auto ldL = [&](int t) -> float2 {
            const int tc = t < TT ? t : TT - 1;
            return *(const float2*)(ebase + (size_t)tc * BB * NN + base);
        };
        auto ldH = [&](int t) -> float2 {
            const int tc = t < TT ? t : TT - 1;
            return *(const float2*)(ebase + (size_t)tc * BB * NN + base + 32);
        };

        auto STEP = [&](int t, float2 el, float2 eh) {
            if (t >= t1v) return;
            const int   d  = probe();
            const float sD = __int_as_float((127 - d) << 23);
            // w for the 4 A-row groups: states {base, base+1, base+32, base+33}
            const _Float16 h0 = (_Float16)(__expf(el.x) * sD);
            const _Float16 h1 = (_Float16)(__expf(el.y) * sD);
            const _Float16 h2 = (_Float16)(__expf(eh.x) * sD);
            const _Float16 h3 = (_Float16)(__expf(eh.y) * sD);
            const half8_t s0 = {h0,h0,h0,h0,h0,h0,h0,h0};
            const half8_t s1 = {h1,h1,h1,h1,h1,h1,h1,h1};
            const half8_t s2 = {h2,h2,h2,h2,h2,h2,h2,h2};
            const half8_t s3 = {h3,h3,h3,h3,h3,h3,h3,h3};
            const half8_t A00 = Af[0][0] * s0, A01 = Af[0][1] * s0;
            const half8_t A10 = Af[1][0] * s1, A11 = Af[1][1] * s1;
            const half8_t A20 = Af[2][0] * s2, A21 = Af[2][1] * s2;
            const half8_t A30 = Af[3][0] * s3, A31 = Af[3][1] * s3;
            #pragma unroll
            for (int n = 0; n < 4; ++n) {
                const f32x4 aA0 = __builtin_amdgcn_mfma_f32_16x16x32_f16(A00, Bt0[n].h, zero4, 0, 0, 0);
                const f32x4 aA1 = __builtin_amdgcn_mfma_f32_16x16x32_f16(A10, Bt0[n].h, zero4, 0, 0, 0);
                const f32x4 aA2 = __builtin_amdgcn_mfma_f32_16x16x32_f16(A20, Bt0[n].h, zero4, 0, 0, 0);
                const f32x4 aA3 = __builtin_amdgcn_mfma_f32_16x16x32_f16(A30, Bt0[n].h, zero4, 0, 0, 0);
                const f32x4 ac0 = __builtin_amdgcn_mfma_f32_16x16x32_f16(A01, Bt1[n].h, aA0, 0, 0, 0);
                const f32x4 ac1 = __builtin_amdgcn_mfma_f32_16x16x32_f16(A11, Bt1[n].h, aA1, 0, 0, 0);
                const f32x4 ac2 = __builtin_amdgcn_mfma_f32_16x16x32_f16(A21, Bt1[n].h, aA2, 0, 0, 0);
                const f32x4 ac3 = __builtin_amdgcn_mfma_f32_16x16x32_f16(A31, Bt1[n].h, aA3, 0, 0, 0);
                #pragma unroll
                for (int r = 0; r < 4; ++r) {
                    Bt0[n].u[r] = __builtin_bit_cast(int, __builtin_amdgcn_cvt_pkrtz(ac0[r], ac1[r]));
                    Bt1[n].u[r] = __builtin_bit_cast(int, __builtin_amdgcn_cvt_pkrtz(ac2[r], ac3[r]));
                }
            }
            e_acc += d + 2;   // +2 restores the 0.25=2^-2 folded into A (exact)
        };

        if (t0 < t1v) {
            const int ng = (t1v - t0 + 3) >> 2;   // 4-step groups
            float2 pl0 = ldL(t0 + 0), ph0 = ldH(t0 + 0);
            float2 pl1 = ldL(t0 + 1), ph1 = ldH(t0 + 1);
            float2 pl2 = ldL(t0 + 2), ph2 = ldH(t0 + 2);
            float2 pl3 = ldL(t0 + 3), ph3 = ldH(t0 + 3);
            #pragma unroll 1
            for (int gi = 0; gi < ng; ++gi) {
                const int tg = t0 + 4 * gi;
                const float2 cl0 = pl0, ch0 = ph0, cl1 = pl1, ch1 = ph1;
                const float2 cl2 = pl2, ch2 = ph2, cl3 = pl3, ch3 = ph3;
                pl0 = ldL(tg + 4); ph0 = ldH(tg + 4);
                pl1 = ldL(tg + 5); ph1 = ldH(tg + 5);
                pl2 = ldL(tg + 6); ph2 = ldH(tg + 6);
                pl3 = ldL(tg + 7); ph3 = ldH(tg + 7);
                STEP(tg + 0, cl0, ch0);
                STEP(tg + 1, cl1, ch1);
                STEP(tg + 2, cl2, ch2);
                STEP(tg + 3, cl3, ch3);
            }
        }

        // store P~_c to LDS, row-major f16 with XOR swizzle (byte ^= (row&7)<<4)
        {
            unsigned short* Pc = &Pmat[c][0][0];
            #pragma unroll
            for (int n = 0; n < 4; ++n) {
                const int col = 16 * n + m15;
                #pragma unroll
                for (int r = 0; r < 4; ++r) {
                    const int k0 = 8 * q + 2 * r;
                    {
                        const int pv = Bt0[n].u[r];
                        *(unsigned short*)((char*)Pc + ((((k0    ) * NN + col) * 2) ^ (((k0    ) & 7) << 4))) = (unsigned short)(pv & 0xffff);
                        *(unsigned short*)((char*)Pc + ((((k0 + 1) * NN + col) * 2) ^ (((k0 + 1) & 7) << 4))) = (unsigned short)((unsigned)pv >> 16);
                    }
                    {
                        const int pv = Bt1[n].u[r];
                        const int k1 = 32 + k0;
                        *(unsigned short*)((char*)Pc + ((((k1    ) * NN + col) * 2) ^ (((k1    ) & 7) << 4))) = (unsigned short)(pv & 0xffff);
                        *(unsigned short*)((char*)Pc + ((((k1 + 1) * NN + col) * 2) ^ (((k1 + 1) & 7) << 4))) = (unsigned short)((unsigned)pv >> 16);
                    }
                }
            }
        }
        if (k == 0) esum[c] = e_acc;
    } else {
        // ---- wave 7: fused gold score for batch b (overlaps the chunk scans) ----
        int tvals[TT / 64];
        #pragma unroll
        for (int i = 0; i < TT / 64; ++i)
            tvals[i] = target[(size_t)(64 * i + k) * BB + b];

        float g = 0.f;
        int prev_last = 0;
        #pragma unroll
        for (int i = 0; i < TT / 64; ++i) {
            const int tt = 64 * i + k;
            const int tgt = tvals[i];
            int tprev = __shfl_up(tvals[i], 1, 64);
            if (k == 0) tprev = prev_last;                       // carry across i
            prev_last = __builtin_amdgcn_readlane(tvals[i], 63);
            if (tt < len) {
                float v = emit[((size_t)tt * BB + b) * NN + tgt];
                v += (tt == 0) ? strans[tgt] : trans[tprev * NN + tgt];
                if (tt == len - 1) v += etrans[tgt];
                g += v;
            }
        }
        g = wave_sum(g);
        if (k == 0) atomicAdd(out, -g);
    }

    __syncthreads();

    // ---- combine + epilogue: wave 0 only ----
    if (tid < 64) {
        // t=0 init: u~0 = exp(alpha0 - m0), redistributed once through ibuf
        const int sL = ((k & 8) << 2) | (q << 3) | (k & 7);
        const float a0 = emit[(size_t)b * NN + sL] + strans[sL];
        const float m0 = bcast_lane(a0, 0);   // sL(lane0) == 0
        ibuf[sL] = __expf(a0 - m0);
        asm volatile("" ::: "memory");

        float uL[8], uH[8];
        {
            const f32x4 i0 = *(const f32x4*)&ibuf[8 * q + 0];
            const f32x4 i1 = *(const f32x4*)&ibuf[8 * q + 4];
            const f32x4 i2 = *(const f32x4*)&ibuf[32 + 8 * q + 0];
            const f32x4 i3 = *(const f32x4*)&ibuf[32 + 8 * q + 4];
            #pragma unroll
            for (int j = 0; j < 4; ++j) {
                uL[j] = i0[j]; uL[4 + j] = i1[j];
                uH[j] = i2[j]; uH[4 + j] = i3[j];
            }
        }
        AFrag Bf0, Bf1;
        #pragma unroll
        for (int r = 0; r < 4; ++r) {
            Bf0.u[r] = __builtin_bit_cast(int, __builtin_amdgcn_cvt_pkrtz(uL[2 * r], uL[2 * r + 1]));
            Bf1.u[r] = __builtin_bit_cast(int, __builtin_amdgcn_cvt_pkrtz(uH[2 * r], uH[2 * r + 1]));
        }

        int E = 0;
        #pragma unroll 1
        for (int cc = 0; cc < NCHUNK; ++cc) {
            // A-frags: A[m][kk] = P~_cc[sigma(g,m)][kk] (rows swizzled in LDS)
            half8_t Ac[4][2];
            const char* rp = (const char*)&Pmat[cc][0][0];
            #pragma unroll
            for (int g = 0; g < 4; ++g) {
                const int row = 32 * (g >> 1) + (g & 1) + base;
                Ac[g][0] = *(const half8_t*)(rp + (((row * NN + 8 * q) * 2)      ^ ((row & 7) << 4)));
                Ac[g][1] = *(const half8_t*)(rp + (((row * NN + 32 + 8 * q) * 2) ^ ((row & 7) << 4)));
            }
            const f32x4 aA0 = __builtin_amdgcn_mfma_f32_16x16x32_f16(Ac[0][0], Bf0.h, zero4, 0, 0, 0);
            const f32x4 aA1 = __builtin_amdgcn_mfma_f32_16x16x32_f16(Ac[1][0], Bf0.h, zero4, 0, 0, 0);
            const f32x4 aA2 = __builtin_amdgcn_mfma_f32_16x16x32_f16(Ac[2][0], Bf0.h, zero4, 0, 0, 0);
            const f32x4 aA3 = __builtin_amdgcn_mfma_f32_16x16x32_f16(Ac[3][0], Bf0.h, zero4, 0, 0, 0);
            const f32x4 ac0 = __builtin_amdgcn_mfma_f32_16x16x32_f16(Ac[0][1], Bf1.h, aA0, 0, 0, 0);
            const f32x4 ac1 = __builtin_amdgcn_mfma_f32_16x16x32_f16(Ac[1][1], Bf1.h, aA1, 0, 0, 0);
            const f32x4 ac2 = __builtin_amdgcn_mfma_f32_16x16x32_f16(Ac[2][1], Bf1.h, aA2, 0, 0, 0);
            const f32x4 ac3 = __builtin_amdgcn_mfma_f32_16x16x32_f16(Ac[3][1], Bf1.h, aA3, 0, 0, 0);

            const int e = (int)((__builtin_amdgcn_readfirstlane(__float_as_uint(ac0[0])) >> 23) & 0xff) - 127 + CGUARD;
            const float sE = __int_as_float((127 - e) << 23);
            #pragma unroll
            for (int r = 0; r < 4; ++r) {
                uL[2 * r]     = ac0[r] * sE;
                uL[2 * r + 1] = ac1[r] * sE;
                uH[2 * r]     = ac2[r] * sE;
                uH[2 * r + 1] = ac3[r] * sE;
            }
            #pragma unroll
            for (int r = 0; r < 4; ++r) {
                Bf0.u[r] = __builtin_bit_cast(int, __builtin_amdgcn_cvt_pkrtz(uL[2 * r], uL[2 * r + 1]));
                Bf1.u[r] = __builtin_bit_cast(int, __builtin_amdgcn_cvt_pkrtz(uH[2 * r], uH[2 * r + 1]));
            }
            E += esum[cc] + e;
        }

        // logZ_b = m0 + ln2*E + logsumexp over the 16 per-lane states
        const f32x4 el0 = *(const f32x4*)&etrans[8 * q + 0];
        const f32x4 el1 = *(const f32x4*)&etrans[8 * q + 4];
        const f32x4 eh0 = *(const f32x4*)&etrans[32 + 8 * q + 0];
        const f32x4 eh1 = *(const f32x4*)&etrans[32 + 8 * q + 4];

        float l[16];
        #pragma unroll
        for (int j = 0; j < 4; ++j) {
            l[j]      = __logf(uL[j])     + el0[j];
            l[4 + j]  = __logf(uL[4 + j]) + el1[j];
            l[8 + j]  = __logf(uH[j])     + eh0[j];
            l[12 + j] = __logf(uH[4 + j]) + eh1[j];
        }
        float mx = l[0];
        #pragma unroll
        for (int j = 1; j < 16; ++j) mx = fmaxf(mx, l[j]);
        mx = fmaxf(mx, __shfl_xor(mx, 16, 64));
        mx = fmaxf(mx, __shfl_xor(mx, 32, 64));
        float sm = 0.f;
        #pragma unroll
        for (int j = 0; j < 16; ++j) sm += __expf(l[j] - mx);
        sm += __shfl_xor(sm, 16, 64);
        sm += __shfl_xor(sm, 32, 64);
        const float logZ_b = m0 + LN2F * (float)E + mx + __logf(sm);

        if (k == 0) atomicAdd(out, logZ_b);
    }
}

extern "C" void kernel_launch(void* const* d_in, const int* in_sizes, int n_in,
                              void* d_out, int out_size, void* d_ws, size_t ws_size,
                              hipStream_t stream) {
    const float* emit   = (const float*)d_in[0];
    const float* trans  = (const float*)d_in[1];
    const float* strans = (const float*)d_in[2];
    const float* etrans = (const float*)d_in[3];
    const int*   target = (const int*)d_in[4];
    const void*  mask   = d_in[5];
    float* out = (float*)d_out;

    hipLaunchKernelGGL(zero_kernel, dim3(1), dim3(64), 0, stream, out);
    hipLaunchKernelGGL(crf_fwd_kernel, dim3(BB), dim3(512), 0, stream,
                       emit, trans, strans, etrans, target, mask, out);
}

// Round 5
// 232.973 us; speedup vs baseline: 1.0083x; 1.0083x over previous
//
#include <hip/hip_runtime.h>

#define TT 512
#define BB 512
#define NN 64
#define LN2F 0.69314718055994530942f

typedef float f32x4 __attribute__((ext_vector_type(4)));

__device__ __forceinline__ float wave_max(float v) {
    #pragma unroll
    for (int off = 32; off > 0; off >>= 1)
        v = fmaxf(v, __shfl_xor(v, off, 64));
    return v;
}

__device__ __forceinline__ float wave_sum(float v) {
    #pragma unroll
    for (int off = 32; off > 0; off >>= 1)
        v += __shfl_xor(v, off, 64);
    return v;
}

__device__ __forceinline__ int wave_sum_i(int v) {
    #pragma unroll
    for (int off = 32; off > 0; off >>= 1)
        v += __shfl_xor(v, off, 64);
    return v;
}

__device__ __forceinline__ float bcast_lane(float v, int lane) {
    return __uint_as_float(__builtin_amdgcn_readlane(__float_as_uint(v), lane));
}

// async global->LDS DMA, 4 bytes/lane: LDS dest = uniform base + lane*4.
__device__ __forceinline__ void async4(const float* g, float* l) {
    __builtin_amdgcn_global_load_lds(
        (const __attribute__((address_space(1))) unsigned int*)g,
        (__attribute__((address_space(3))) unsigned int*)l,
        4, 0, 0);
}

// Zero the scalar output (harness poisons d_out with 0xAA before every launch).
__global__ void zero_kernel(float* __restrict__ out) {
    if (threadIdx.x == 0 && blockIdx.x == 0) out[0] = 0.0f;
}

// r17: VALU matvec (no MFMA). Lane j owns state j: u_j in a register, the
// full E-column exp(trans[k][j]) k=0..63 in 64 VGPRs. Per step:
//   ds_write u -> 16 broadcast ds_read_b128 (all 64 u_k) -> 64 v_fmac in 8
//   independent chains -> add tree -> u' = y * w.
// The LDS write->read turnaround is safe wave-internally (DS pipe is in-order
// per wave); compiler ordering pinned by asm memory fences.
// Normalization is r14's delayed power-of-2 scheme, now fully off-chain:
// d = exponent(lane0's u) via readfirstlane in the shadow of the next step's
// read+FMA phase; 2^-d folds into the next w with one off-chain mul;
// e_sum += d exact. f32 range makes the loose scheme trivially safe
// (E in e^±0.44, w in e^±4.5 -> spread << f32 range).
// DMA ring / len / init / LSE epilogue / gold are r12-verbatim (verified).
__global__ __launch_bounds__(64) void crf_fwd_kernel(
    const float* __restrict__ emit,
    const float* __restrict__ trans,
    const float* __restrict__ strans,
    const float* __restrict__ etrans,
    const int*   __restrict__ target,
    const void*  __restrict__ maskp,
    float* __restrict__ out)
{
    const int b = blockIdx.x;
    const int k = threadIdx.x;

    __shared__ float sem[2][8][NN];            // 4 KB emit ring: [half][slot][state]
    __shared__ __align__(16) float ubuf[NN];   // u broadcast buffer

    const int*           mi32 = (const int*)maskp;
    const unsigned char* mi8  = (const unsigned char*)maskp;
    // mask[0,:] is all-true (lengths >= 1): byte encoding -> word0 == 0x01010101.
    const bool bytemode = (mi32[0] == 0x01010101);

    // len[b] = sum_t mask[t,b] (mask monotone per column) — one-time cost.
    int cnt = 0;
    #pragma unroll
    for (int i = 0; i < TT / 64; ++i) {
        const size_t tb = (size_t)(i * 64 + k) * BB + b;
        cnt += bytemode ? (mi8[tb] != 0) : (mi32[tb] != 0);
    }
    const int len = wave_sum_i(cnt);   // wave-uniform

    const float* ecol = emit + (size_t)b * NN + k;   // row stride BB*NN

    // Prologue: DMA rows 1..8 into half 0 (rows 1..8 always exist: TT=512).
    #pragma unroll
    for (int s = 0; s < 8; ++s)
        async4(ecol + (size_t)(1 + s) * BB * NN, &sem[0][s][0]);

    // E-column in registers: E[i] = exp(trans[i][k]) (coalesced loads over i).
    float E[NN];
    #pragma unroll
    for (int i = 0; i < NN; ++i)
        E[i] = __expf(trans[i * NN + k]);

    // t = 0: u = exp(alpha0 - m0); lane0's u == 1 exactly -> initial d = 0.
    const float alpha0 = ecol[0] + strans[k];
    const float m0 = bcast_lane(alpha0, 0);
    float u = __expf(alpha0 - m0);
    ubuf[k] = u;
    asm volatile("" ::: "memory");

    int   e_sum = 0;
    int   d  = 0;
    float sD = 1.0f;

    // One step in the exp domain.
    auto do_step = [&](float wraw) {
        const float wcur = wraw * sD;   // sD from previous step's probe (ready)

        // broadcast-read all 64 u values (uniform addresses: conflict-free)
        const f32x4 U0  = *(const f32x4*)&ubuf[ 0];
        const f32x4 U1  = *(const f32x4*)&ubuf[ 4];
        const f32x4 U2  = *(const f32x4*)&ubuf[ 8];
        const f32x4 U3  = *(const f32x4*)&ubuf[12];
        const f32x4 U4  = *(const f32x4*)&ubuf[16];
        const f32x4 U5  = *(const f32x4*)&ubuf[20];
        const f32x4 U6  = *(const f32x4*)&ubuf[24];
        const f32x4 U7  = *(const f32x4*)&ubuf[28];
        const f32x4 U8  = *(const f32x4*)&ubuf[32];
        const f32x4 U9  = *(const f32x4*)&ubuf[36];
        const f32x4 U10 = *(const f32x4*)&ubuf[40];
        const f32x4 U11 = *(const f32x4*)&ubuf[44];
        const f32x4 U12 = *(const f32x4*)&ubuf[48];
        const f32x4 U13 = *(const f32x4*)&ubuf[52];
        const f32x4 U14 = *(const f32x4*)&ubuf[56];
        const f32x4 U15 = *(const f32x4*)&ubuf[60];

        // 64 FMAs in 8 independent chains (8 deep each)
        float a0 = E[ 0] * U0[0], a1 = E[ 1] * U0[1], a2 = E[ 2] * U0[2], a3 = E[ 3] * U0[3];
        float a4 = E[ 4] * U1[0], a5 = E[ 5] * U1[1], a6 = E[ 6] * U1[2], a7 = E[ 7] * U1[3];
        a0 = fmaf(E[ 8], U2[0], a0); a1 = fmaf(E[ 9], U2[1], a1); a2 = fmaf(E[10], U2[2], a2); a3 = fmaf(E[11], U2[3], a3);
        a4 = fmaf(E[12], U3[0], a4); a5 = fmaf(E[13], U3[1], a5); a6 = fmaf(E[14], U3[2], a6); a7 = fmaf(E[15], U3[3], a7);
        a0 = fmaf(E[16], U4[0], a0); a1 = fmaf(E[17], U4[1], a1); a2 = fmaf(E[18], U4[2], a2); a3 = fmaf(E[19], U4[3], a3);
        a4 = fmaf(E[20], U5[0], a4); a5 = fmaf(E[21], U5[1], a5); a6 = fmaf(E[22], U5[2], a6); a7 = fmaf(E[23], U5[3], a7);
        a0 = fmaf(E[24], U6[0], a0); a1 = fmaf(E[25], U6[1], a1); a2 = fmaf(E[26], U6[2], a2); a3 = fmaf(E[27], U6[3], a3);
        a4 = fmaf(E[28], U7[0], a4); a5 = fmaf(E[29], U7[1], a5); a6 = fmaf(E[30], U7[2], a6); a7 = fmaf(E[31], U7[3], a7);
        a0 = fmaf(E[32], U8[0], a0); a1 = fmaf(E[33], U8[1], a1); a2 = fmaf(E[34], U8[2], a2); a3 = fmaf(E[35], U8[3], a3);
        a4 = fmaf(E[36], U9[0], a4); a5 = fmaf(E[37], U9[1], a5); a6 = fmaf(E[38], U9[2], a6); a7 = fmaf(E[39], U9[3], a7);
        a0 = fmaf(E[40], U10[0], a0); a1 = fmaf(E[41], U10[1], a1); a2 = fmaf(E[42], U10[2], a2); a3 = fmaf(E[43], U10[3], a3);
        a4 = fmaf(E[44], U11[0], a4); a5 = fmaf(E[45], U11[1], a5); a6 = fmaf(E[46], U11[2], a6); a7 = fmaf(E[47], U11[3], a7);
        a0 = fmaf(E[48], U12[0], a0); a1 = fmaf(E[49], U12[1], a1); a2 = fmaf(E[50], U12[2], a2); a3 = fmaf(E[51], U12[3], a3);
        a4 = fmaf(E[52], U13[0], a4); a5 = fmaf(E[53], U13[1], a5); a6 = fmaf(E[54], U13[2], a6); a7 = fmaf(E[55], U13[3], a7);
        a0 = fmaf(E[56], U14[0], a0); a1 = fmaf(E[57], U14[1], a1); a2 = fmaf(E[58], U14[2], a2); a3 = fmaf(E[59], U14[3], a3);
        a4 = fmaf(E[60], U15[0], a4); a5 = fmaf(E[61], U15[1], a5); a6 = fmaf(E[62], U15[2], a6); a7 = fmaf(E[63], U15[3], a7);

        const float y = ((a0 + a4) + (a1 + a5)) + ((a2 + a6) + (a3 + a7));

        u = y * wcur;
        ubuf[k] = u;
        asm volatile("" ::: "memory");

        // (off-chain, in the shadow of the next step's read+FMA phase)
        e_sum += d;   // d folded into wcur this step
        d = (int)((__builtin_amdgcn_readfirstlane(__float_as_uint(u)) >> 23) & 0xff) - 127;
        sD = __int_as_float((127 - d) << 23);
    };

    int t = 1;
    int half = 0;
    // Invariant at block top: rows t..t+7 are in sem[half][0..7] — their DMAs
    // were issued >= 1 block (~8 steps) ago, so the vmcnt wait is free.
    for (; t + 8 <= len; t += 8) {
        // (1) read this block's emit rows into registers (off the u-chain)
        const float v0 = sem[half][0][k], v1 = sem[half][1][k];
        const float v2 = sem[half][2][k], v3 = sem[half][3][k];
        const float v4 = sem[half][4][k], v5 = sem[half][5][k];
        const float v6 = sem[half][6][k], v7 = sem[half][7][k];

        // (2) issue next block's DMAs into the other half (clamped at TT-1;
        //     overshoot rows are never consumed)
        #pragma unroll
        for (int s = 0; s < 8; ++s) {
            const int tf = (t + 8 + s < TT) ? (t + 8 + s) : (TT - 1);
            async4(ecol + (size_t)tf * BB * NN, &sem[half ^ 1][s][0]);
        }

        // (3) exps off the u-chain, then 8 steps
        const float w0 = __expf(v0), w1 = __expf(v1), w2 = __expf(v2), w3 = __expf(v3);
        const float w4 = __expf(v4), w5 = __expf(v5), w6 = __expf(v6), w7 = __expf(v7);
        do_step(w0); do_step(w1); do_step(w2); do_step(w3);
        do_step(w4); do_step(w5); do_step(w6); do_step(w7);

        half ^= 1;
    }

    // Remainder (< 8 steps): rows t..len-1 are already in sem[half][...].
    for (int s = 0; t < len; ++t, ++s)
        do_step(__expf(sem[half][s][k]));

    // logZ_b = S + logsumexp_k(log(u_k) + etrans[k]),  S = m0 + ln2*e_sum
    const float la = __logf(u) + etrans[k];   // u==0 -> -inf -> exp -> 0: fine
    const float m2 = wave_max(la);
    const float sm = wave_sum(__expf(la - m2));
    const float logZ_b = m0 + LN2F * (float)e_sum + m2 + __logf(sm);

    // ---- fused gold score for batch b: lane k covers t = 64*i + k ----
    int tvals[TT / 64];
    #pragma unroll
    for (int i = 0; i < TT / 64; ++i)
        tvals[i] = target[(size_t)(64 * i + k) * BB + b];

    float g = 0.f;
    int prev_last = 0;
    #pragma unroll
    for (int i = 0; i < TT / 64; ++i) {
        const int tt = 64 * i + k;
        const int tgt = tvals[i];
        int tprev = __shfl_up(tvals[i], 1, 64);
        if (k == 0) tprev = prev_last;                       // carry across i
        prev_last = __builtin_amdgcn_readlane(tvals[i], 63);
        if (tt < len) {
            float v = emit[((size_t)tt * BB + b) * NN + tgt];
            v += (tt == 0) ? strans[tgt] : trans[tprev * NN + tgt];
            if (tt == len - 1) v += etrans[tgt];
            g += v;
        }
    }
    g = wave_sum(g);

    if (k == 0) atomicAdd(out, logZ_b - g);
}

extern "C" void kernel_launch(void* const* d_in, const int* in_sizes, int n_in,
                              void* d_out, int out_size, void* d_ws, size_t ws_size,
                              hipStream_t stream) {
    const float* emit   = (const float*)d_in[0];
    const float* trans  = (const float*)d_in[1];
    const float* strans = (const float*)d_in[2];
    const float* etrans = (const float*)d_in[3];
    const int*   target = (const int*)d_in[4];
    const void*  mask   = d_in[5];
    float* out = (float*)d_out;

    hipLaunchKernelGGL(zero_kernel, dim3(1), dim3(64), 0, stream, out);
    hipLaunchKernelGGL(crf_fwd_kernel, dim3(BB), dim3(64), 0, stream,
                       emit, trans, strans, etrans, target, mask, out);
}

// Round 6
// 168.684 us; speedup vs baseline: 1.3925x; 1.3811x over previous
//
#include <hip/hip_runtime.h>

#define TT 512
#define BB 512
#define NN 64
#define LN2F 0.69314718055994530942f
#define SCH 64           // chunk length in steps; 8 chunks cover t = 1..511
#define EXACT_THRESH 32  // boundary chunks shorter than this are re-run exactly

typedef _Float16 half8_t __attribute__((ext_vector_type(8)));
typedef float    f32x4   __attribute__((ext_vector_type(4)));

union AFrag { int u[4]; half8_t h; };

__device__ __forceinline__ float wave_max(float v) {
    #pragma unroll
    for (int off = 32; off > 0; off >>= 1)
        v = fmaxf(v, __shfl_xor(v, off, 64));
    return v;
}

__device__ __forceinline__ float wave_sum(float v) {
    #pragma unroll
    for (int off = 32; off > 0; off >>= 1)
        v += __shfl_xor(v, off, 64);
    return v;
}

__device__ __forceinline__ int wave_sum_i(int v) {
    #pragma unroll
    for (int off = 32; off > 0; off >>= 1)
        v += __shfl_xor(v, off, 64);
    return v;
}

__device__ __forceinline__ float bcast_lane(float v, int lane) {
    return __uint_as_float(__builtin_amdgcn_readlane(__float_as_uint(v), lane));
}

// Zero the scalar output (harness poisons d_out with 0xAA before every launch).
__global__ void zero_kernel(float* __restrict__ out) {
    if (threadIdx.x == 0 && blockIdx.x == 0) out[0] = 0.0f;
}

// r18: Perron-Frobenius rank-1 chunking. u_{t+1} = diag(w_t)E~^T u_t with E
// strictly positive: Birkhoff contraction kappa = tanh(Delta/4) ~ 0.45/step
// (Delta <= 4 max|trans| ~ 1.9; diag scaling is a Hilbert isometry), so any
// >=32-step chunk product M_c is rank-1 to <= 6e-12 relative. Block = 1 batch,
// 9 waves:
//   wave 0   : F_0 = M_0 u_0 (exact chunk on the true init vector)
//   waves 1-7: F_c = M_c 1 (fwd) AND R_c = M_c^T 1 (bwd), two independent
//              r12-style 497-cyc matvec chains interleaved in one wave
//              (issue 2x~90 < chain ~500 -> no wall increase)
//   wave 8   : gold score (r16-verified), atomicAdd(out, -g)
// Combine (wave 0, after one barrier) uses the EXACT rank-1 identity
//   M_c x = F_c (R_c^T x)/(1^T F_c)
// in log domain; the boundary chunk (containing step len-1) is re-run exactly
// when it has < 32 steps (not enough contraction). Serial depth: 64 + <=31
// steps vs 511. Per-step math and power-of-2 bookkeeping (e from pre-w probe
// +4 guard, e_sum += e+2) are r12-verbatim; bwd steps use transposed B-frags
// and multiply w on the INPUT (M_t^T = E~ diag(w_t)), iterating t descending.
__global__ __launch_bounds__(576) void crf_fwd_kernel(
    const float* __restrict__ emit,
    const float* __restrict__ trans,
    const float* __restrict__ strans,
    const float* __restrict__ etrans,
    const int*   __restrict__ target,
    const void*  __restrict__ maskp,
    float* __restrict__ out)
{
    const int b   = blockIdx.x;
    const int tid = threadIdx.x;
    const int k   = tid & 63;
    const int wv  = tid >> 6;   // 0..7 chunk waves, 8 = gold

    __shared__ float FL[8][NN];   // scaled F_c
    __shared__ float RL[8][NN];   // scaled R_c
    __shared__ int   EFs[8], ERs[8];

    const int*           mi32 = (const int*)maskp;
    const unsigned char* mi8  = (const unsigned char*)maskp;
    // mask[0,:] is all-true (lengths >= 1): byte encoding -> word0 == 0x01010101.
    const bool bytemode = (mi32[0] == 0x01010101);

    // len[b] = sum_t mask[t,b] (mask monotone per column)
    int cnt = 0;
    #pragma unroll
    for (int i = 0; i < TT / 64; ++i) {
        const size_t tb = (size_t)(i * 64 + k) * BB + b;
        cnt += bytemode ? (mi8[tb] != 0) : (mi32[tb] != 0);
    }
    const int len = wave_sum_i(cnt);   // wave-uniform

    const int  q    = k >> 4;
    const int  nlo  = k & 15;
    const bool bit4 = (k & 16) != 0;
    const bool bit5 = (k & 32) != 0;

    const float* eptr = emit + (size_t)b * NN + k;   // row stride BB*NN

    // bpermute byte-addresses (r12): A frag (kh, reg r) sources lane 32kh+8q+2r.
    int addrs[8];
    #pragma unroll
    for (int kh = 0; kh < 2; ++kh)
        #pragma unroll
        for (int r = 0; r < 4; ++r)
            addrs[4 * kh + r] = 128 * kh + 32 * q + 8 * r;

    const f32x4 zero4 = {0.f, 0.f, 0.f, 0.f};

    auto ldrow = [&](int t) -> float {
        t = t < 0 ? 0 : (t >= TT ? TT - 1 : t);
        return eptr[(size_t)t * BB * NN];
    };

    // B fragments. fwd (y_n = sum_k x_k exp(trans[k][n])): r12-verbatim.
    // bwd (y_n = sum_k x_k exp(trans[n][k])): transposed load.
    half8_t BfF[4][2], BfB[4][2];
    if (wv < 8) {
        #pragma unroll
        for (int g = 0; g < 4; ++g) {
            #pragma unroll
            for (int kh = 0; kh < 2; ++kh) {
                AFrag bf, bb;
                #pragma unroll
                for (int jp = 0; jp < 4; ++jp) {
                    const int krow = 32 * kh + 8 * q + 2 * jp;
                    const int ncol = 16 * g + nlo;
                    const float f0 = 0.25f * __expf(trans[(krow + 0) * NN + ncol]);
                    const float f1 = 0.25f * __expf(trans[(krow + 1) * NN + ncol]);
                    bf.u[jp] = __builtin_bit_cast(int, __builtin_amdgcn_cvt_pkrtz(f0, f1));
                    const float g0 = 0.25f * __expf(trans[ncol * NN + (krow + 0)]);
                    const float g1 = 0.25f * __expf(trans[ncol * NN + (krow + 1)]);
                    bb.u[jp] = __builtin_bit_cast(int, __builtin_amdgcn_cvt_pkrtz(g0, g1));
                }
                BfF[g][kh] = bf.h;
                BfB[g][kh] = bb.h;
            }
        }
    }

    // r12-verified matvec: pack -> 8 bpermute -> 8 MFMA (K-halves C-chained)
    // -> lane k selects its own output state via 3 cndmasks.
    auto matvec = [&](float x, const half8_t Bf[4][2]) -> float {
        const float uo = __int_as_float(
            __builtin_amdgcn_mov_dpp(__float_as_int(x), 0xB1, 0xF, 0xF, true));
        const int pkv = __builtin_bit_cast(int, __builtin_amdgcn_cvt_pkrtz(x, uo));
        AFrag a0f, a1f;
        #pragma unroll
        for (int r = 0; r < 4; ++r) {
            a0f.u[r] = __builtin_amdgcn_ds_bpermute(addrs[r],     pkv);
            a1f.u[r] = __builtin_amdgcn_ds_bpermute(addrs[4 + r], pkv);
        }
        const f32x4 aA0 = __builtin_amdgcn_mfma_f32_16x16x32_f16(a0f.h, Bf[0][0], zero4, 0, 0, 0);
        const f32x4 aA1 = __builtin_amdgcn_mfma_f32_16x16x32_f16(a0f.h, Bf[1][0], zero4, 0, 0, 0);
        const f32x4 aA2 = __builtin_amdgcn_mfma_f32_16x16x32_f16(a0f.h, Bf[2][0], zero4, 0, 0, 0);
        const f32x4 aA3 = __builtin_amdgcn_mfma_f32_16x16x32_f16(a0f.h, Bf[3][0], zero4, 0, 0, 0);
        const f32x4 ac0 = __builtin_amdgcn_mfma_f32_16x16x32_f16(a1f.h, Bf[0][1], aA0, 0, 0, 0);
        const f32x4 ac1 = __builtin_amdgcn_mfma_f32_16x16x32_f16(a1f.h, Bf[1][1], aA1, 0, 0, 0);
        const f32x4 ac2 = __builtin_amdgcn_mfma_f32_16x16x32_f16(a1f.h, Bf[2][1], aA2, 0, 0, 0);
        const f32x4 ac3 = __builtin_amdgcn_mfma_f32_16x16x32_f16(a1f.h, Bf[3][1], aA3, 0, 0, 0);
        const float sLo = bit4 ? ac1[0] : ac0[0];
        const float sHi = bit4 ? ac3[0] : ac2[0];
        return bit5 ? sHi : sLo;
    };

    float uF = 1.f, uB = 1.f;
    int   eF = 0,  eB = 0;
    float m0 = 0.f;

    // fwd step: y = matvec(u); e from PRE-w probe (+4 guard); u = ldexp(y*w,-e)
    auto stepF = [&](float w) {
        const float yown = matvec(uF, BfF);
        const int e = (int)((__builtin_amdgcn_readfirstlane(__float_as_uint(yown)) >> 23) & 0xff) - 127 + 4;
        uF = ldexpf(yown * w, -e);
        eF += e + 2;   // +2 restores the 0.25=2^-2 folded into B (exact)
    };
    // bwd step (M_t^T = E~ diag(w_t)): v = u*w first, then matvec.
    auto stepB = [&](float w) {
        const float yown = matvec(uB * w, BfB);
        const int e = (int)((__builtin_amdgcn_readfirstlane(__float_as_uint(yown)) >> 23) & 0xff) - 127 + 4;
        uB = ldexpf(yown, -e);
        eB += e + 2;
    };

    if (wv < 8) {
        const int t0  = 1 + SCH * wv;
        const int nst = max(0, min(len - t0, SCH));
        const bool dob = (wv > 0);

        if (wv == 0) {
            const float alpha0 = eptr[0] + strans[k];
            m0 = bcast_lane(alpha0, 0);
            uF = __expf(alpha0 - m0);
        }

        const int tL = t0 + nst - 1;   // bwd iterates t descending from tL
        float fa = ldrow(t0 + 0), fb = ldrow(t0 + 1), fc = ldrow(t0 + 2), fd = ldrow(t0 + 3);
        float ba = ldrow(tL - 0), bbv = ldrow(tL - 1), bcv = ldrow(tL - 2), bdv = ldrow(tL - 3);
        int i = 0;
        for (; i + 4 <= nst; i += 4) {
            const float wf0 = __expf(fa), wf1 = __expf(fb), wf2 = __expf(fc), wf3 = __expf(fd);
            const float wb0 = __expf(ba), wb1 = __expf(bbv), wb2 = __expf(bcv), wb3 = __expf(bdv);
            fa  = ldrow(t0 + i + 4); fb  = ldrow(t0 + i + 5); fc  = ldrow(t0 + i + 6); fd  = ldrow(t0 + i + 7);
            ba  = ldrow(tL - i - 4); bbv = ldrow(tL - i - 5); bcv = ldrow(tL - i - 6); bdv = ldrow(tL - i - 7);
            stepF(wf0); if (dob) stepB(wb0);
            stepF(wf1); if (dob) stepB(wb1);
            stepF(wf2); if (dob) stepB(wb2);
            stepF(wf3); if (dob) stepB(wb3);
        }
        if (i     < nst) { stepF(__expf(fa)); if (dob) stepB(__expf(ba));  }
        if (i + 1 < nst) { stepF(__expf(fb)); if (dob) stepB(__expf(bbv)); }
        if (i + 2 < nst) { stepF(__expf(fc)); if (dob) stepB(__expf(bcv)); }

        FL[wv][k] = uF;
        RL[wv][k] = uB;
        if (k == 0) { EFs[wv] = eF; ERs[wv] = eB; }
    } else {
        // ---- wave 8: fused gold score (overlaps the chunk chains) ----
        int tvals[TT / 64];
        #pragma unroll
        for (int i = 0; i < TT / 64; ++i)
            tvals[i] = target[(size_t)(64 * i + k) * BB + b];

        float g = 0.f;
        int prev_last = 0;
        #pragma unroll
        for (int i = 0; i < TT / 64; ++i) {
            const int tt = 64 * i + k;
            const int tgt = tvals[i];
            int tprev = __shfl_up(tvals[i], 1, 64);
            if (k == 0) tprev = prev_last;                       // carry across i
            prev_last = __builtin_amdgcn_readlane(tvals[i], 63);
            if (tt < len) {
                float v = emit[((size_t)tt * BB + b) * NN + tgt];
                v += (tt == 0) ? strans[tgt] : trans[tprev * NN + tgt];
                if (tt == len - 1) v += etrans[tgt];
                g += v;
            }
        }
        g = wave_sum(g);
        if (k == 0) atomicAdd(out, -g);
    }

    __syncthreads();

    // ---- combine + (maybe) exact boundary replay + epilogue: wave 0 ----
    if (wv == 0) {
        float Ltot = LN2F * (float)EFs[0];
        float x = FL[0][k];

        const int  Bc  = (len >= 2) ? ((len - 2) / SCH) : 0;
        const int  tB0 = 1 + SCH * Bc;
        const int  sB  = len - tB0;                       // steps in boundary chunk
        const bool exact = (Bc >= 1) && (sB < EXACT_THRESH);
        const int  Cend  = exact ? Bc - 1 : Bc;

        // rank-1 applications: M_c x = F_c (R_c^T x)/(1^T F_c); 2^EF cancels.
        for (int c = 1; c <= Cend; ++c) {
            const float num = wave_sum(RL[c][k] * x);
            const float den = wave_sum(FL[c][k]);
            Ltot += __logf(num / den) + LN2F * (float)ERs[c];
            x = FL[c][k];
        }

        if (exact) {
            // replay the short boundary chunk exactly from x
            uF = x; eF = 0;
            float pa = ldrow(tB0 + 0), pb = ldrow(tB0 + 1), pc = ldrow(tB0 + 2), pd = ldrow(tB0 + 3);
            int i = 0;
            for (; i + 4 <= sB; i += 4) {
                const float w0 = __expf(pa), w1 = __expf(pb), w2 = __expf(pc), w3 = __expf(pd);
                pa = ldrow(tB0 + i + 4); pb = ldrow(tB0 + i + 5);
                pc = ldrow(tB0 + i + 6); pd = ldrow(tB0 + i + 7);
                stepF(w0); stepF(w1); stepF(w2); stepF(w3);
            }
            if (i     < sB) stepF(__expf(pa));
            if (i + 1 < sB) stepF(__expf(pb));
            if (i + 2 < sB) stepF(__expf(pc));
            x = uF;
            Ltot += LN2F * (float)eF;
        }

        // logZ_b = m0 + Ltot + logsumexp_k(log(x_k) + etrans[k])
        const float la = __logf(x) + etrans[k];   // x==0 -> -inf -> exp -> 0: fine
        const float m2 = wave_max(la);
        const float sm = wave_sum(__expf(la - m2));
        const float logZ_b = m0 + Ltot + m2 + __logf(sm);

        if (k == 0) atomicAdd(out, logZ_b);
    }
}

extern "C" void kernel_launch(void* const* d_in, const int* in_sizes, int n_in,
                              void* d_out, int out_size, void* d_ws, size_t ws_size,
                              hipStream_t stream) {
    const float* emit   = (const float*)d_in[0];
    const float* trans  = (const float*)d_in[1];
    const float* strans = (const float*)d_in[2];
    const float* etrans = (const float*)d_in[3];
    const int*   target = (const int*)d_in[4];
    const void*  mask   = d_in[5];
    float* out = (float*)d_out;

    hipLaunchKernelGGL(zero_kernel, dim3(1), dim3(64), 0, stream, out);
    hipLaunchKernelGGL(crf_fwd_kernel, dim3(BB), dim3(576), 0, stream,
                       emit, trans, strans, etrans, target, mask, out);
}

// Round 7
// 148.504 us; speedup vs baseline: 1.5818x; 1.1359x over previous
//
#include <hip/hip_runtime.h>

#define TT 512
#define BB 512
#define NN 64
#define LN2F 0.69314718055994530942f
#define SCH 64           // chunk length; 8 chunks cover t = 1..511
#define EXACT_THRESH 32  // boundary chunks shorter than this are replayed exactly

typedef _Float16 half8_t __attribute__((ext_vector_type(8)));
typedef float    f32x4   __attribute__((ext_vector_type(4)));

union AFrag { int u[4]; half8_t h; };

__device__ __forceinline__ float wave_max(float v) {
    #pragma unroll
    for (int off = 32; off > 0; off >>= 1)
        v = fmaxf(v, __shfl_xor(v, off, 64));
    return v;
}

__device__ __forceinline__ float wave_sum(float v) {
    #pragma unroll
    for (int off = 32; off > 0; off >>= 1)
        v += __shfl_xor(v, off, 64);
    return v;
}

__device__ __forceinline__ int wave_sum_i(int v) {
    #pragma unroll
    for (int off = 32; off > 0; off >>= 1)
        v += __shfl_xor(v, off, 64);
    return v;
}

// Zero the scalar output (harness poisons d_out with 0xAA before every launch).
__global__ void zero_kernel(float* __restrict__ out) {
    if (threadIdx.x == 0 && blockIdx.x == 0) out[0] = 0.0f;
}

// r19: rank-1 chunking (r18 math, verified) executed on 16-column MFMAs
// (r16 feedback algebra, verified). Block = 1 batch, 3 waves:
//   wave 0 (F): 8 fwd chunk-chains as B-columns 0..7 (8..15 duplicates) of one
//               8-MFMA step: u_c' = diag(w_t) E^T u_c, all chunks at once.
//   wave 1 (B): 7 bwd chains R_c = M_c^T 1: v' = E (w_t ⊙ v), rows descending.
//   wave 2:     gold score (r18-verbatim), atomicAdd(out, -g).
// Feedback is lane-local (sigma permutation): lane L's acc[g][r] = its column's
// u' at state 32*(g>>1)+(g&1)+8q+2r -> repack to the next B-fragment directly.
// Per-column normalization: r14's 1-step-delayed power-of-2 scheme; the probe
// is one off-chain ds_bpermute of column c's state-0 y (lane c, q=0);
// e_acc += d+2 exact per step. Boundary chunk (sB steps) snapshotted at the
// single wave-uniform event i==sB. Combine (rank-1 identity), optional exact
// replay (<32 steps, replicated columns, readfirstlane probe), LSE: r18 math.
__global__ __launch_bounds__(192) void crf_fwd_kernel(
    const float* __restrict__ emit,
    const float* __restrict__ trans,
    const float* __restrict__ strans,
    const float* __restrict__ etrans,
    const int*   __restrict__ target,
    const void*  __restrict__ maskp,
    float* __restrict__ out)
{
    const int b   = blockIdx.x;
    const int tid = threadIdx.x;
    const int k   = tid & 63;
    const int wv  = tid >> 6;   // 0 = fwd chains, 1 = bwd chains, 2 = gold

    __shared__ float FL[8][NN];   // scaled F_c (state-indexed)
    __shared__ float RL[8][NN];   // scaled R_c
    __shared__ float xbuf[NN];
    __shared__ int   esF[8], esB[8];

    const int*           mi32 = (const int*)maskp;
    const unsigned char* mi8  = (const unsigned char*)maskp;
    // mask[0,:] is all-true (lengths >= 1): byte encoding -> word0 == 0x01010101.
    const bool bytemode = (mi32[0] == 0x01010101);

    // len[b] = sum_t mask[t,b] (monotone mask)
    int cnt = 0;
    #pragma unroll
    for (int i = 0; i < TT / 64; ++i) {
        const size_t tb = (size_t)(i * 64 + k) * BB + b;
        cnt += bytemode ? (mi8[tb] != 0) : (mi32[tb] != 0);
    }
    const int len = wave_sum_i(cnt);   // wave-uniform

    const int q    = k >> 4;
    const int m15  = k & 15;
    const int base = 8 * (m15 >> 2) + 2 * (m15 & 3);   // sigma(g,m)=32*(g>>1)+(g&1)+base

    const int  Bc    = (len >= 2) ? ((len - 2) / SCH) : 0;   // boundary chunk id (0..7)
    const int  sB    = len - (1 + SCH * Bc);                 // its step count (0..64)
    const bool exact = (Bc >= 1) && (sB < EXACT_THRESH);

    const f32x4 zero4 = {0.f, 0.f, 0.f, 0.f};
    float m0loc = 0.f;

    // Persist F-wave registers needed after the barrier (Af reused in replay).
    half8_t Af[4][2];
    float uLo[8], uHi[8];

    if (wv <= 1) {
        const bool fwd = (wv == 0);
        const int cF  = m15 & 7;                 // column's chunk (8..15 duplicate)
        const int t0  = 1 + SCH * cF;
        const int nst = min(max(len - t0, 0), SCH);
        const int tLq = t0 + nst - 1;            // bwd starts here, descending

        // A-fragments: F: A[m][kk]=0.25exp(trans[kk][sigma(g,m)]) (r16-verbatim);
        //              B: A[m][kk]=0.25exp(trans[sigma(g,m)][kk]) (transposed).
        #pragma unroll
        for (int g = 0; g < 4; ++g) {
            const int nsg = 32 * (g >> 1) + (g & 1) + base;
            #pragma unroll
            for (int kh = 0; kh < 2; ++kh) {
                AFrag af;
                #pragma unroll
                for (int jp = 0; jp < 4; ++jp) {
                    const int krow = 32 * kh + 8 * q + 2 * jp;
                    float e0, e1;
                    if (fwd) {
                        e0 = 0.25f * __expf(trans[(krow + 0) * NN + nsg]);
                        e1 = 0.25f * __expf(trans[(krow + 1) * NN + nsg]);
                    } else {
                        e0 = 0.25f * __expf(trans[nsg * NN + krow + 0]);
                        e1 = 0.25f * __expf(trans[nsg * NN + krow + 1]);
                    }
                    af.u[jp] = __builtin_bit_cast(int, __builtin_amdgcn_cvt_pkrtz(e0, e1));
                }
                Af[g][kh] = af.h;
            }
        }

        // Initial u: F col 0 = exp(alpha0 - m0) at lane's 16 states, else 1.
        if (fwd) {
            const float* p0 = emit + (size_t)b * NN;   // emit[0][b][*]
            m0loc = p0[0] + strans[0];
            const f32x4 e0 = *(const f32x4*)(p0 + 8 * q);
            const f32x4 e1 = *(const f32x4*)(p0 + 8 * q + 4);
            const f32x4 e2 = *(const f32x4*)(p0 + 32 + 8 * q);
            const f32x4 e3 = *(const f32x4*)(p0 + 32 + 8 * q + 4);
            const f32x4 s0 = *(const f32x4*)(strans + 8 * q);
            const f32x4 s1 = *(const f32x4*)(strans + 8 * q + 4);
            const f32x4 s2 = *(const f32x4*)(strans + 32 + 8 * q);
            const f32x4 s3 = *(const f32x4*)(strans + 32 + 8 * q + 4);
            #pragma unroll
            for (int j = 0; j < 4; ++j) {
                uLo[j]     = (m15 == 0) ? __expf(e0[j] + s0[j] - m0loc) : 1.f;
                uLo[4 + j] = (m15 == 0) ? __expf(e1[j] + s1[j] - m0loc) : 1.f;
                uHi[j]     = (m15 == 0) ? __expf(e2[j] + s2[j] - m0loc) : 1.f;
                uHi[4 + j] = (m15 == 0) ? __expf(e3[j] + s3[j] - m0loc) : 1.f;
            }
        } else {
            #pragma unroll
            for (int j = 0; j < 8; ++j) { uLo[j] = 1.f; uHi[j] = 1.f; }
        }

        // Initial per-column scale: d from the column-group max (xor16/32 mixes
        // exactly lanes {c, c+16, c+32, c+48}).
        float mx = uLo[0];
        #pragma unroll
        for (int j = 1; j < 8; ++j) mx = fmaxf(mx, uLo[j]);
        #pragma unroll
        for (int j = 0; j < 8; ++j) mx = fmaxf(mx, uHi[j]);
        mx = fmaxf(mx, __shfl_xor(mx, 16, 64));
        mx = fmaxf(mx, __shfl_xor(mx, 32, 64));
        int   d  = (int)((__float_as_uint(mx) >> 23) & 0xff) - 127 + 4;
        float sD = __int_as_float((127 - d) << 23);
        int   e_acc = 0;

        // Initial pack (F chains feed B-fragments directly; B packs in-step).
        AFrag BF0, BF1;
        #pragma unroll
        for (int r = 0; r < 4; ++r) {
            BF0.u[r] = __builtin_bit_cast(int, __builtin_amdgcn_cvt_pkrtz(uLo[2 * r], uLo[2 * r + 1]));
            BF1.u[r] = __builtin_bit_cast(int, __builtin_amdgcn_cvt_pkrtz(uHi[2 * r], uHi[2 * r + 1]));
        }

        float sLo[8], sHi[8];
        int   eSnap = 0;
        #pragma unroll
        for (int j = 0; j < 8; ++j) { sLo[j] = uLo[j]; sHi[j] = uHi[j]; }

        auto rowOf = [&](int j) -> int {
            int r = fwd ? (t0 + j) : (tLq - j);
            r = r < 0 ? 0 : (r > TT - 1 ? TT - 1 : r);
            return r;
        };
        auto LDW = [&](int j, f32x4& r0, f32x4& r1, f32x4& r2, f32x4& r3) {
            const int rr = rowOf(j);
            const float* p = emit + ((size_t)rr * BB + b) * NN;
            r0 = *(const f32x4*)(p + 8 * q);
            r1 = *(const f32x4*)(p + 8 * q + 4);
            r2 = *(const f32x4*)(p + 32 + 8 * q);
            r3 = *(const f32x4*)(p + 32 + 8 * q + 4);
        };
        auto SNAP = [&]() {
            #pragma unroll
            for (int j = 0; j < 8; ++j) { sLo[j] = uLo[j]; sHi[j] = uHi[j]; }
            eSnap = e_acc;
        };

        auto STEP = [&](f32x4& r0, f32x4& r1, f32x4& r2, f32x4& r3, int jn) {
            // w·2^-d for this step (sD from the previous step's probe)
            float wt0[8], wt1[8];
            #pragma unroll
            for (int jj = 0; jj < 4; ++jj) {
                wt0[jj]     = __expf(r0[jj]) * sD;
                wt0[4 + jj] = __expf(r1[jj]) * sD;
                wt1[jj]     = __expf(r2[jj]) * sD;
                wt1[4 + jj] = __expf(r3[jj]) * sD;
            }
            LDW(jn, r0, r1, r2, r3);   // prefetch 2 steps ahead

            int pf;
            if (fwd) {
                const f32x4 aA0 = __builtin_amdgcn_mfma_f32_16x16x32_f16(Af[0][0], BF0.h, zero4, 0, 0, 0);
                const f32x4 aA1 = __builtin_amdgcn_mfma_f32_16x16x32_f16(Af[1][0], BF0.h, zero4, 0, 0, 0);
                const f32x4 aA2 = __builtin_amdgcn_mfma_f32_16x16x32_f16(Af[2][0], BF0.h, zero4, 0, 0, 0);
                const f32x4 aA3 = __builtin_amdgcn_mfma_f32_16x16x32_f16(Af[3][0], BF0.h, zero4, 0, 0, 0);
                const f32x4 ac0 = __builtin_amdgcn_mfma_f32_16x16x32_f16(Af[0][1], BF1.h, aA0, 0, 0, 0);
                const f32x4 ac1 = __builtin_amdgcn_mfma_f32_16x16x32_f16(Af[1][1], BF1.h, aA1, 0, 0, 0);
                const f32x4 ac2 = __builtin_amdgcn_mfma_f32_16x16x32_f16(Af[2][1], BF1.h, aA2, 0, 0, 0);
                const f32x4 ac3 = __builtin_amdgcn_mfma_f32_16x16x32_f16(Af[3][1], BF1.h, aA3, 0, 0, 0);
                pf = __builtin_amdgcn_ds_bpermute(m15 << 2, __builtin_bit_cast(int, ac0[0]));
                #pragma unroll
                for (int r = 0; r < 4; ++r) {
                    uLo[2 * r]     = ac0[r] * wt0[2 * r];
                    uLo[2 * r + 1] = ac1[r] * wt0[2 * r + 1];
                    uHi[2 * r]     = ac2[r] * wt1[2 * r];
                    uHi[2 * r + 1] = ac3[r] * wt1[2 * r + 1];
                }
                #pragma unroll
                for (int r = 0; r < 4; ++r) {
                    BF0.u[r] = __builtin_bit_cast(int, __builtin_amdgcn_cvt_pkrtz(uLo[2 * r], uLo[2 * r + 1]));
                    BF1.u[r] = __builtin_bit_cast(int, __builtin_amdgcn_cvt_pkrtz(uHi[2 * r], uHi[2 * r + 1]));
                }
            } else {
                // bwd: v' = E (w ⊙ v)
                float v0[8], v1[8];
                #pragma unroll
                for (int j = 0; j < 8; ++j) { v0[j] = uLo[j] * wt0[j]; v1[j] = uHi[j] * wt1[j]; }
                #pragma unroll
                for (int r = 0; r < 4; ++r) {
                    BF0.u[r] = __builtin_bit_cast(int, __builtin_amdgcn_cvt_pkrtz(v0[2 * r], v0[2 * r + 1]));
                    BF1.u[r] = __builtin_bit_cast(int, __builtin_amdgcn_cvt_pkrtz(v1[2 * r], v1[2 * r + 1]));
                }
                const f32x4 aA0 = __builtin_amdgcn_mfma_f32_16x16x32_f16(Af[0][0], BF0.h, zero4, 0, 0, 0);
                const f32x4 aA1 = __builtin_amdgcn_mfma_f32_16x16x32_f16(Af[1][0], BF0.h, zero4, 0, 0, 0);
                const f32x4 aA2 = __builtin_amdgcn_mfma_f32_16x16x32_f16(Af[2][0], BF0.h, zero4, 0, 0, 0);
                const f32x4 aA3 = __builtin_amdgcn_mfma_f32_16x16x32_f16(Af[3][0], BF0.h, zero4, 0, 0, 0);
                const f32x4 ac0 = __builtin_amdgcn_mfma_f32_16x16x32_f16(Af[0][1], BF1.h, aA0, 0, 0, 0);
                const f32x4 ac1 = __builtin_amdgcn_mfma_f32_16x16x32_f16(Af[1][1], BF1.h, aA1, 0, 0, 0);
                const f32x4 ac2 = __builtin_amdgcn_mfma_f32_16x16x32_f16(Af[2][1], BF1.h, aA2, 0, 0, 0);
                const f32x4 ac3 = __builtin_amdgcn_mfma_f32_16x16x32_f16(Af[3][1], BF1.h, aA3, 0, 0, 0);
                pf = __builtin_amdgcn_ds_bpermute(m15 << 2, __builtin_bit_cast(int, ac0[0]));
                #pragma unroll
                for (int r = 0; r < 4; ++r) {
                    uLo[2 * r]     = ac0[r];
                    uLo[2 * r + 1] = ac1[r];
                    uHi[2 * r]     = ac2[r];
                    uHi[2 * r + 1] = ac3[r];
                }
            }
            e_acc += d + 2;   // +2 restores the 0.25=2^-2 folded into A (exact)
            d  = ((pf >> 23) & 0xff) - 127 + 4;
            sD = __int_as_float((127 - d) << 23);
        };

        // main loop: prefetch depth 2 via named buffer rotation
        f32x4 a0, a1, a2, a3, b0, b1, b2, b3;
        LDW(0, a0, a1, a2, a3);
        LDW(1, b0, b1, b2, b3);
        #pragma unroll 1
        for (int i = 0; i < SCH; i += 2) {
            if (i == sB) SNAP();
            STEP(a0, a1, a2, a3, min(i + 2, SCH - 1));
            if (i + 1 == sB) SNAP();
            STEP(b0, b1, b2, b3, min(i + 3, SCH - 1));
        }
        if (sB == SCH) SNAP();

        // store results (only columns 0..7; duplicates skipped)
        if (m15 < 8) {
            const bool us = (m15 == Bc);
            float* dst = fwd ? &FL[m15][0] : &RL[m15][0];
            f32x4 w0, w1, w2, w3;
            #pragma unroll
            for (int j = 0; j < 4; ++j) {
                w0[j] = us ? sLo[j]     : uLo[j];
                w1[j] = us ? sLo[4 + j] : uLo[4 + j];
                w2[j] = us ? sHi[j]     : uHi[j];
                w3[j] = us ? sHi[4 + j] : uHi[4 + j];
            }
            *(f32x4*)(dst + 8 * q)          = w0;
            *(f32x4*)(dst + 8 * q + 4)      = w1;
            *(f32x4*)(dst + 32 + 8 * q)     = w2;
            *(f32x4*)(dst + 32 + 8 * q + 4) = w3;
            if (q == 0) (fwd ? esF : esB)[m15] = us ? eSnap : e_acc;
        }
    } else {
        // ---- wave 2: fused gold score (overlaps the chains) ----
        int tvals[TT / 64];
        #pragma unroll
        for (int i = 0; i < TT / 64; ++i)
            tvals[i] = target[(size_t)(64 * i + k) * BB + b];

        float g = 0.f;
        int prev_last = 0;
        #pragma unroll
        for (int i = 0; i < TT / 64; ++i) {
            const int tt = 64 * i + k;
            const int tgt = tvals[i];
            int tprev = __shfl_up(tvals[i], 1, 64);
            if (k == 0) tprev = prev_last;                       // carry across i
            prev_last = __builtin_amdgcn_readlane(tvals[i], 63);
            if (tt < len) {
                float v = emit[((size_t)tt * BB + b) * NN + tgt];
                v += (tt == 0) ? strans[tgt] : trans[tprev * NN + tgt];
                if (tt == len - 1) v += etrans[tgt];
                g += v;
            }
        }
        g = wave_sum(g);
        if (k == 0) atomicAdd(out, -g);
    }

    __syncthreads();

    // ---- combine + optional exact replay + epilogue: wave 0 ----
    if (wv == 0) {
        float x    = FL[0][k];
        float Ltot = LN2F * (float)esF[0];
        const int Cend = exact ? (Bc - 1) : Bc;

        // rank-1: M_c x = F_c (R_c^T x)/(1^T F_c); chunk scales via esB.
        for (int c = 1; c <= Cend; ++c) {
            const float num = wave_sum(RL[c][k] * x);
            const float den = wave_sum(FL[c][k]);
            Ltot += __logf(num / den) + LN2F * (float)esB[c];
            x = FL[c][k];
        }

        if (exact) {
            // replay the short boundary chunk exactly (replicated columns;
            // wave-uniform d via readfirstlane = col0/state0, r12 scheme)
            xbuf[k] = x;
            asm volatile("" ::: "memory");
            float vLo[8], vHi[8];
            #pragma unroll
            for (int j = 0; j < 8; ++j) {
                vLo[j] = xbuf[8 * q + j];
                vHi[j] = xbuf[32 + 8 * q + j];
            }
            AFrag B0, B1;
            #pragma unroll
            for (int r = 0; r < 4; ++r) {
                B0.u[r] = __builtin_bit_cast(int, __builtin_amdgcn_cvt_pkrtz(vLo[2 * r], vLo[2 * r + 1]));
                B1.u[r] = __builtin_bit_cast(int, __builtin_amdgcn_cvt_pkrtz(vHi[2 * r], vHi[2 * r + 1]));
            }
            int eR = 0;
            const int t0B = 1 + SCH * Bc;
            #pragma unroll 1
            for (int j = 0; j < sB; ++j) {
                const int rr = t0B + j;   // <= len-1 <= 511
                const float* p = emit + ((size_t)rr * BB + b) * NN;
                const f32x4 r0 = *(const f32x4*)(p + 8 * q);
                const f32x4 r1 = *(const f32x4*)(p + 8 * q + 4);
                const f32x4 r2 = *(const f32x4*)(p + 32 + 8 * q);
                const f32x4 r3 = *(const f32x4*)(p + 32 + 8 * q + 4);
                float wt0[8], wt1[8];
                #pragma unroll
                for (int jj = 0; jj < 4; ++jj) {
                    wt0[jj]     = __expf(r0[jj]);
                    wt0[4 + jj] = __expf(r1[jj]);
                    wt1[jj]     = __expf(r2[jj]);
                    wt1[4 + jj] = __expf(r3[jj]);
                }
                const f32x4 aA0 = __builtin_amdgcn_mfma_f32_16x16x32_f16(Af[0][0], B0.h, zero4, 0, 0, 0);
                const f32x4 aA1 = __builtin_amdgcn_mfma_f32_16x16x32_f16(Af[1][0], B0.h, zero4, 0, 0, 0);
                const f32x4 aA2 = __builtin_amdgcn_mfma_f32_16x16x32_f16(Af[2][0], B0.h, zero4, 0, 0, 0);
                const f32x4 aA3 = __builtin_amdgcn_mfma_f32_16x16x32_f16(Af[3][0], B0.h, zero4, 0, 0, 0);
                const f32x4 ac0 = __builtin_amdgcn_mfma_f32_16x16x32_f16(Af[0][1], B1.h, aA0, 0, 0, 0);
                const f32x4 ac1 = __builtin_amdgcn_mfma_f32_16x16x32_f16(Af[1][1], B1.h, aA1, 0, 0, 0);
                const f32x4 ac2 = __builtin_amdgcn_mfma_f32_16x16x32_f16(Af[2][1], B1.h, aA2, 0, 0, 0);
                const f32x4 ac3 = __builtin_amdgcn_mfma_f32_16x16x32_f16(Af[3][1], B1.h, aA3, 0, 0, 0);
                const int e = (int)((__builtin_amdgcn_readfirstlane(__float_as_uint(ac0[0])) >> 23) & 0xff) - 127 + 4;
                const float sE = __int_as_float((127 - e) << 23);
                #pragma unroll
                for (int r = 0; r < 4; ++r) {
                    vLo[2 * r]     = ac0[r] * wt0[2 * r]     * sE;
                    vLo[2 * r + 1] = ac1[r] * wt0[2 * r + 1] * sE;
                    vHi[2 * r]     = ac2[r] * wt1[2 * r]     * sE;
                    vHi[2 * r + 1] = ac3[r] * wt1[2 * r + 1] * sE;
                }
                #pragma unroll
                for (int r = 0; r < 4; ++r) {
                    B0.u[r] = __builtin_bit_cast(int, __builtin_amdgcn_cvt_pkrtz(vLo[2 * r], vLo[2 * r + 1]));
                    B1.u[r] = __builtin_bit_cast(int, __builtin_amdgcn_cvt_pkrtz(vHi[2 * r], vHi[2 * r + 1]));
                }
                eR += e + 2;
            }
            // write back (all columns identical; duplicate writes benign)
            asm volatile("" ::: "memory");
            *(f32x4*)&xbuf[8 * q]          = *(f32x4*)&vLo[0];
            *(f32x4*)&xbuf[8 * q + 4]      = *(f32x4*)&vLo[4];
            *(f32x4*)&xbuf[32 + 8 * q]     = *(f32x4*)&vHi[0];
            *(f32x4*)&xbuf[32 + 8 * q + 4] = *(f32x4*)&vHi[4];
            asm volatile("" ::: "memory");
            x = xbuf[k];
            Ltot += LN2F * (float)eR;
        }

        // logZ_b = m0 + Ltot + logsumexp_k(log(x_k) + etrans[k])
        const float la = __logf(x) + etrans[k];   // x==0 -> -inf -> exp -> 0: fine
        const float m2 = wave_max(la);
        const float sm = wave_sum(__expf(la - m2));
        const float logZ_b = m0loc + Ltot + m2 + __logf(sm);

        if (k == 0) atomicAdd(out, logZ_b);
    }
}

extern "C" void kernel_launch(void* const* d_in, const int* in_sizes, int n_in,
                              void* d_out, int out_size, void* d_ws, size_t ws_size,
                              hipStream_t stream) {
    const float* emit   = (const float*)d_in[0];
    const float* trans  = (const float*)d_in[1];
    const float* strans = (const float*)d_in[2];
    const float* etrans = (const float*)d_in[3];
    const int*   target = (const int*)d_in[4];
    const void*  mask   = d_in[5];
    float* out = (float*)d_out;

    hipLaunchKernelGGL(zero_kernel, dim3(1), dim3(64), 0, stream, out);
    hipLaunchKernelGGL(crf_fwd_kernel, dim3(BB), dim3(192), 0, stream,
                       emit, trans, strans, etrans, target, mask, out);
}